// Round 1
// baseline (3063.003 us; speedup 1.0000x reference)
//
#include <hip/hip_runtime.h>

#define N_FACES 50000
#define N_EDGES 800000
#define NB      16
#define HID     256
#define NOUT    512

// ---------- wave helpers ----------
__device__ __forceinline__ float wave_sum(float v) {
#pragma unroll
  for (int o = 32; o; o >>= 1) v += __shfl_xor(v, o, 64);
  return v;
}
__device__ __forceinline__ float wave_max(float v) {
#pragma unroll
  for (int o = 32; o; o >>= 1) v = fmaxf(v, __shfl_xor(v, o, 64));
  return v;
}

// ---------- CSR build ----------
__global__ void k_hist(const int* __restrict__ dst, int* __restrict__ cnt) {
  int e = blockIdx.x * blockDim.x + threadIdx.x;
  if (e < N_EDGES) atomicAdd(&cnt[dst[e]], 1);
}

__global__ void k_scan(const int* __restrict__ cnt, int* __restrict__ row_ptr) {
  __shared__ int sh[1024];
  __shared__ int carry;
  int t = threadIdx.x;
  if (t == 0) carry = 0;
  __syncthreads();
  for (int base = 0; base <= N_FACES; base += 1024) {
    int i = base + t;
    int v = (i < N_FACES) ? cnt[i] : 0;
    sh[t] = v;
    __syncthreads();
    for (int off = 1; off < 1024; off <<= 1) {
      int x = (t >= off) ? sh[t - off] : 0;
      __syncthreads();
      sh[t] += x;
      __syncthreads();
    }
    if (i <= N_FACES) row_ptr[i] = carry + sh[t] - v;  // exclusive
    __syncthreads();
    if (t == 1023) carry += sh[1023];
    __syncthreads();
  }
}

__global__ void k_scatter(const int* __restrict__ dst, const int* __restrict__ row_ptr,
                          int* __restrict__ fill, int* __restrict__ edge_ids) {
  int e = blockIdx.x * blockDim.x + threadIdx.x;
  if (e < N_EDGES) {
    int d = dst[e];
    int p = atomicAdd(&fill[d], 1);
    edge_ids[row_ptr[d] + p] = e;
  }
}

// ---------- encoders + mean aggregation (one wave per node) ----------
__global__ void k_encode(const float* __restrict__ xf, const float* __restrict__ xe,
                         const float* __restrict__ fW, const float* __restrict__ fB,
                         const float* __restrict__ fG, const float* __restrict__ fBe,
                         const float* __restrict__ eW, const float* __restrict__ eB,
                         const float* __restrict__ eG, const float* __restrict__ eBe,
                         const int* __restrict__ row_ptr, const int* __restrict__ eid,
                         float* __restrict__ h) {
  int lane = threadIdx.x & 63;
  int n = blockIdx.x * 4 + (threadIdx.x >> 6);
  if (n >= N_FACES) return;

  float x[7];
#pragma unroll
  for (int k = 0; k < 7; ++k) x[k] = xf[n * 7 + k];
  float y[4];
#pragma unroll
  for (int j = 0; j < 4; ++j) {
    int c = lane + 64 * j;
    float a = fB[c];
#pragma unroll
    for (int k = 0; k < 7; ++k) a += x[k] * fW[k * HID + c];
    y[j] = fmaxf(a, 0.f);
  }
  float s = y[0] + y[1] + y[2] + y[3];
  float s2 = y[0] * y[0] + y[1] * y[1] + y[2] * y[2] + y[3] * y[3];
  s = wave_sum(s); s2 = wave_sum(s2);
  float mu = s * (1.f / HID);
  float rs = rsqrtf(fmaxf(s2 * (1.f / HID) - mu * mu, 0.f) + 1e-5f);
  float hv[4];
#pragma unroll
  for (int j = 0; j < 4; ++j) {
    int c = lane + 64 * j;
    hv[j] = (y[j] - mu) * rs * fG[c] + fBe[c];
  }

  int e0 = row_ptr[n], e1 = row_ptr[n + 1];
  float acc[4] = {0.f, 0.f, 0.f, 0.f};
  for (int t = e0; t < e1; ++t) {
    int e = eid[t];
    float z[6];
#pragma unroll
    for (int k = 0; k < 6; ++k) z[k] = xe[e * 6 + k];
    float w[4];
#pragma unroll
    for (int j = 0; j < 4; ++j) {
      int c = lane + 64 * j;
      float a = eB[c];
#pragma unroll
      for (int k = 0; k < 6; ++k) a += z[k] * eW[k * HID + c];
      w[j] = fmaxf(a, 0.f);
    }
    float t1 = w[0] + w[1] + w[2] + w[3];
    float t2 = w[0] * w[0] + w[1] * w[1] + w[2] * w[2] + w[3] * w[3];
    t1 = wave_sum(t1); t2 = wave_sum(t2);
    float mu2 = t1 * (1.f / HID);
    float rs2 = rsqrtf(fmaxf(t2 * (1.f / HID) - mu2 * mu2, 0.f) + 1e-5f);
#pragma unroll
    for (int j = 0; j < 4; ++j) {
      int c = lane + 64 * j;
      acc[j] += (w[j] - mu2) * rs2 * eG[c] + eBe[c];
    }
  }
  float inv = (e1 > e0) ? 1.f / (float)(e1 - e0) : 0.f;
#pragma unroll
  for (int j = 0; j < 4; ++j) h[(size_t)n * HID + lane + 64 * j] = hv[j] + acc[j] * inv;
}

// ---------- f = h @ W  (16 nodes per block, 256 threads) ----------
#define GM 16
__global__ void k_gemm256(const float* __restrict__ h, const float* __restrict__ W,
                          float* __restrict__ f) {
  __shared__ float hs[GM][HID];
  int n0 = blockIdx.x * GM;
  int c = threadIdx.x;
#pragma unroll
  for (int m = 0; m < GM; ++m) hs[m][c] = h[(size_t)(n0 + m) * HID + c];
  __syncthreads();
  float acc[GM];
#pragma unroll
  for (int m = 0; m < GM; ++m) acc[m] = 0.f;
  for (int k = 0; k < HID; ++k) {
    float w = W[k * HID + c];
#pragma unroll
    for (int m = 0; m < GM; ++m) acc[m] += hs[m][k] * w;
  }
#pragma unroll
  for (int m = 0; m < GM; ++m) f[(size_t)(n0 + m) * HID + c] = acc[m];
}

// ---------- el/er (one wave per node) ----------
__global__ void k_elr(const float* __restrict__ f, const float* __restrict__ al,
                      const float* __restrict__ ar, float* __restrict__ el,
                      float* __restrict__ er) {
  int lane = threadIdx.x & 63;
  int n = blockIdx.x * 4 + (threadIdx.x >> 6);
  if (n >= N_FACES) return;
  float4 v = reinterpret_cast<const float4*>(f)[(size_t)n * 64 + lane];
  float4 a = reinterpret_cast<const float4*>(al)[lane];
  float4 b = reinterpret_cast<const float4*>(ar)[lane];
  float pl = v.x * a.x + v.y * a.y + v.z * a.z + v.w * a.w;
  float pr = v.x * b.x + v.y * b.y + v.z * b.z + v.w * b.w;
#pragma unroll
  for (int o = 1; o < 16; o <<= 1) {
    pl += __shfl_xor(pl, o, 64);
    pr += __shfl_xor(pr, o, 64);
  }
  if ((lane & 15) == 0) {
    el[n * 4 + (lane >> 4)] = pl;
    er[n * 4 + (lane >> 4)] = pr;
  }
}

// ---------- GAT attention + aggregation + bias/ReLU/LN (one wave per node) ----------
__global__ void k_gat(const float* __restrict__ f, const float* __restrict__ el,
                      const float* __restrict__ er, const int* __restrict__ row_ptr,
                      const int* __restrict__ eid, const int* __restrict__ src,
                      const float* __restrict__ bias, const float* __restrict__ g,
                      const float* __restrict__ be, float* __restrict__ h) {
  int lane = threadIdx.x & 63;
  int n = blockIdx.x * 4 + (threadIdx.x >> 6);
  if (n >= N_FACES) return;
  int e0 = row_ptr[n], e1 = row_ptr[n + 1];
  float4 ern = reinterpret_cast<const float4*>(er)[n];

  float m0 = -1e30f, m1 = -1e30f, m2 = -1e30f, m3 = -1e30f;
  for (int t = e0; t < e1; ++t) {
    int s = src[eid[t]];
    float4 e4 = reinterpret_cast<const float4*>(el)[s];
    float w;
    w = e4.x + ern.x; w = w > 0.f ? w : 0.2f * w; m0 = fmaxf(m0, w);
    w = e4.y + ern.y; w = w > 0.f ? w : 0.2f * w; m1 = fmaxf(m1, w);
    w = e4.z + ern.z; w = w > 0.f ? w : 0.2f * w; m2 = fmaxf(m2, w);
    w = e4.w + ern.w; w = w > 0.f ? w : 0.2f * w; m3 = fmaxf(m3, w);
  }
  float s0 = 0.f, s1 = 0.f, s2 = 0.f, s3 = 0.f;
  for (int t = e0; t < e1; ++t) {
    int s = src[eid[t]];
    float4 e4 = reinterpret_cast<const float4*>(el)[s];
    float w;
    w = e4.x + ern.x; w = w > 0.f ? w : 0.2f * w; s0 += __expf(w - m0);
    w = e4.y + ern.y; w = w > 0.f ? w : 0.2f * w; s1 += __expf(w - m1);
    w = e4.z + ern.z; w = w > 0.f ? w : 0.2f * w; s2 += __expf(w - m2);
    w = e4.w + ern.w; w = w > 0.f ? w : 0.2f * w; s3 += __expf(w - m3);
  }
  float i0 = s0 > 0.f ? 1.f / s0 : 0.f;
  float i1 = s1 > 0.f ? 1.f / s1 : 0.f;
  float i2 = s2 > 0.f ? 1.f / s2 : 0.f;
  float i3 = s3 > 0.f ? 1.f / s3 : 0.f;

  float a0 = 0.f, a1 = 0.f, a2 = 0.f, a3 = 0.f;
  for (int t = e0; t < e1; ++t) {
    int s = src[eid[t]];
    float4 e4 = reinterpret_cast<const float4*>(el)[s];
    float w, p;
    const float* fr = f + (size_t)s * HID;
    w = e4.x + ern.x; w = w > 0.f ? w : 0.2f * w; p = __expf(w - m0) * i0; a0 += fr[lane]       * p;
    w = e4.y + ern.y; w = w > 0.f ? w : 0.2f * w; p = __expf(w - m1) * i1; a1 += fr[lane + 64]  * p;
    w = e4.z + ern.z; w = w > 0.f ? w : 0.2f * w; p = __expf(w - m2) * i2; a2 += fr[lane + 128] * p;
    w = e4.w + ern.w; w = w > 0.f ? w : 0.2f * w; p = __expf(w - m3) * i3; a3 += fr[lane + 192] * p;
  }

  float y0 = fmaxf(a0 + bias[lane], 0.f);
  float y1 = fmaxf(a1 + bias[lane + 64], 0.f);
  float y2 = fmaxf(a2 + bias[lane + 128], 0.f);
  float y3 = fmaxf(a3 + bias[lane + 192], 0.f);
  float s = y0 + y1 + y2 + y3;
  float q = y0 * y0 + y1 * y1 + y2 * y2 + y3 * y3;
  s = wave_sum(s); q = wave_sum(q);
  float mu = s * (1.f / HID);
  float rs = rsqrtf(fmaxf(q * (1.f / HID) - mu * mu, 0.f) + 1e-5f);
  size_t base = (size_t)n * HID;
  h[base + lane]       = (y0 - mu) * rs * g[lane]       + be[lane];
  h[base + lane + 64]  = (y1 - mu) * rs * g[lane + 64]  + be[lane + 64];
  h[base + lane + 128] = (y2 - mu) * rs * g[lane + 128] + be[lane + 128];
  h[base + lane + 192] = (y3 - mu) * rs * g[lane + 192] + be[lane + 192];
}

// ---------- gate scores ----------
__global__ void k_gate(const float* __restrict__ h, const float* __restrict__ gw,
                       const float* __restrict__ gb, float* __restrict__ gate) {
  int lane = threadIdx.x & 63;
  int n = blockIdx.x * 4 + (threadIdx.x >> 6);
  if (n >= N_FACES) return;
  float4 v = reinterpret_cast<const float4*>(h)[(size_t)n * 64 + lane];
  float4 w = reinterpret_cast<const float4*>(gw)[lane];
  float p = v.x * w.x + v.y * w.y + v.z * w.z + v.w * w.w;
  p = wave_sum(p);
  if (lane == 0) gate[n] = p + gb[0];
}

// ---------- graph node-range bounds ----------
__global__ void k_bounds(const int* __restrict__ gid, int* __restrict__ gstart,
                         int* __restrict__ gend) {
  int n = blockIdx.x * blockDim.x + threadIdx.x;
  if (n < N_FACES) {
    int g = gid[n];
    atomicMin(&gstart[g], n);
    atomicMax(&gend[g], n + 1);
  }
}

// ---------- per-graph softmax pooling ----------
__global__ void k_pool(const float* __restrict__ h, const float* __restrict__ gate,
                       const int* __restrict__ gid, const int* __restrict__ gstart,
                       const int* __restrict__ gend, float* __restrict__ pooled) {
  int b = blockIdx.x;
  int t = threadIdx.x;
  int lane = t & 63, wid = t >> 6;
  int n0 = gstart[b], n1 = gend[b];
  __shared__ float part[4];
  __shared__ float sh_m, sh_s;

  float m = -1e30f;
  for (int n = n0 + t; n < n1; n += 256)
    if (gid[n] == b) m = fmaxf(m, gate[n]);
  m = wave_max(m);
  if (lane == 0) part[wid] = m;
  __syncthreads();
  if (t == 0) sh_m = fmaxf(fmaxf(part[0], part[1]), fmaxf(part[2], part[3]));
  __syncthreads();
  float bm = sh_m;

  float s = 0.f;
  for (int n = n0 + t; n < n1; n += 256)
    if (gid[n] == b) s += __expf(gate[n] - bm);
  s = wave_sum(s);
  __syncthreads();
  if (lane == 0) part[wid] = s;
  __syncthreads();
  if (t == 0) sh_s = part[0] + part[1] + part[2] + part[3];
  __syncthreads();
  float inv = 1.f / sh_s;

  float acc = 0.f;
  for (int n = n0; n < n1; ++n) {
    if (gid[n] == b) {
      float w = __expf(gate[n] - bm) * inv;
      acc += w * h[(size_t)n * HID + t];
    }
  }
  pooled[b * HID + t] = acc;
}

// ---------- output projection + LN ----------
__global__ void k_out(const float* __restrict__ pooled, const float* __restrict__ oW,
                      const float* __restrict__ oB, const float* __restrict__ oG,
                      const float* __restrict__ oBe, float* __restrict__ feat) {
  int b = blockIdx.x;
  int o = threadIdx.x;  // 512 threads
  int lane = o & 63, wid = o >> 6;
  __shared__ float p[HID];
  __shared__ float partS[8], partQ[8];
  __shared__ float shMu, shRs;
  if (o < HID) p[o] = pooled[b * HID + o];
  __syncthreads();
  float a = oB[o];
  for (int k = 0; k < HID; ++k) a += p[k] * oW[k * NOUT + o];
  float y = fmaxf(a, 0.f);
  float s = wave_sum(y), q = wave_sum(y * y);
  if (lane == 0) { partS[wid] = s; partQ[wid] = q; }
  __syncthreads();
  if (o == 0) {
    float S = 0.f, Q = 0.f;
#pragma unroll
    for (int i = 0; i < 8; ++i) { S += partS[i]; Q += partQ[i]; }
    float mu = S * (1.f / NOUT);
    shMu = mu;
    shRs = rsqrtf(fmaxf(Q * (1.f / NOUT) - mu * mu, 0.f) + 1e-5f);
  }
  __syncthreads();
  feat[b * NOUT + o] = (y - shMu) * shRs * oG[o] + oBe[o];
}

extern "C" void kernel_launch(void* const* d_in, const int* in_sizes, int n_in,
                              void* d_out, int out_size, void* d_ws, size_t ws_size,
                              hipStream_t stream) {
  (void)in_sizes; (void)n_in; (void)out_size; (void)ws_size;
  const float* x_face    = (const float*)d_in[0];
  const float* x_edge    = (const float*)d_in[1];
  const float* face_W    = (const float*)d_in[2];
  const float* face_b    = (const float*)d_in[3];
  const float* face_g    = (const float*)d_in[4];
  const float* face_beta = (const float*)d_in[5];
  const float* edge_W    = (const float*)d_in[6];
  const float* edge_b    = (const float*)d_in[7];
  const float* edge_g    = (const float*)d_in[8];
  const float* edge_beta = (const float*)d_in[9];
  const float* g0_W      = (const float*)d_in[10];
  const float* g0_al     = (const float*)d_in[11];
  const float* g0_ar     = (const float*)d_in[12];
  const float* g0_bias   = (const float*)d_in[13];
  const float* g0_g      = (const float*)d_in[14];
  const float* g0_beta   = (const float*)d_in[15];
  const float* g1_W      = (const float*)d_in[16];
  const float* g1_al     = (const float*)d_in[17];
  const float* g1_ar     = (const float*)d_in[18];
  const float* g1_bias   = (const float*)d_in[19];
  const float* g1_g      = (const float*)d_in[20];
  const float* g1_beta   = (const float*)d_in[21];
  const float* gate_W    = (const float*)d_in[22];
  const float* gate_b    = (const float*)d_in[23];
  const float* out_W     = (const float*)d_in[24];
  const float* out_b     = (const float*)d_in[25];
  const float* out_g     = (const float*)d_in[26];
  const float* out_beta  = (const float*)d_in[27];
  const int*   src       = (const int*)d_in[28];
  const int*   dst       = (const int*)d_in[29];
  const int*   gid       = (const int*)d_in[30];

  char* ws = (char*)d_ws;
  size_t off = 0;
  auto take = [&](size_t bytes) -> char* {
    char* pp = ws + off;
    off += (bytes + 255) & ~(size_t)255;
    return pp;
  };
  int*   cnt      = (int*)take((size_t)N_FACES * 4);
  int*   fill     = (int*)take((size_t)N_FACES * 4);
  int*   row_ptr  = (int*)take((size_t)(N_FACES + 1) * 4);
  int*   edge_ids = (int*)take((size_t)N_EDGES * 4);
  int*   gstart   = (int*)take(64);
  int*   gend     = (int*)take(64);
  float* el       = (float*)take((size_t)N_FACES * 4 * 4);
  float* er       = (float*)take((size_t)N_FACES * 4 * 4);
  float* gate     = (float*)take((size_t)N_FACES * 4);
  float* f        = (float*)take((size_t)N_FACES * HID * 4);

  float* outp   = (float*)d_out;
  float* feat   = outp;
  float* h      = outp + NB * NOUT;
  float* pooled = outp + NB * NOUT + (size_t)N_FACES * HID;

  hipMemsetAsync(cnt, 0, (size_t)N_FACES * 4, stream);
  hipMemsetAsync(fill, 0, (size_t)N_FACES * 4, stream);
  hipMemsetAsync(gstart, 0x7F, 64, stream);
  hipMemsetAsync(gend, 0, 64, stream);

  k_hist<<<(N_EDGES + 255) / 256, 256, 0, stream>>>(dst, cnt);
  k_scan<<<1, 1024, 0, stream>>>(cnt, row_ptr);
  k_scatter<<<(N_EDGES + 255) / 256, 256, 0, stream>>>(dst, row_ptr, fill, edge_ids);

  k_encode<<<N_FACES / 4, 256, 0, stream>>>(x_face, x_edge, face_W, face_b, face_g, face_beta,
                                            edge_W, edge_b, edge_g, edge_beta,
                                            row_ptr, edge_ids, h);
  // GAT layer 0
  k_gemm256<<<N_FACES / GM, 256, 0, stream>>>(h, g0_W, f);
  k_elr<<<N_FACES / 4, 256, 0, stream>>>(f, g0_al, g0_ar, el, er);
  k_gat<<<N_FACES / 4, 256, 0, stream>>>(f, el, er, row_ptr, edge_ids, src,
                                         g0_bias, g0_g, g0_beta, h);
  // GAT layer 1
  k_gemm256<<<N_FACES / GM, 256, 0, stream>>>(h, g1_W, f);
  k_elr<<<N_FACES / 4, 256, 0, stream>>>(f, g1_al, g1_ar, el, er);
  k_gat<<<N_FACES / 4, 256, 0, stream>>>(f, el, er, row_ptr, edge_ids, src,
                                         g1_bias, g1_g, g1_beta, h);
  // pooling + output head
  k_gate<<<N_FACES / 4, 256, 0, stream>>>(h, gate_W, gate_b, gate);
  k_bounds<<<(N_FACES + 255) / 256, 256, 0, stream>>>(gid, gstart, gend);
  k_pool<<<NB, 256, 0, stream>>>(h, gate, gid, gstart, gend, pooled);
  k_out<<<NB, NOUT, 0, stream>>>(pooled, out_W, out_b, out_g, out_beta, feat);
}

// Round 2
// 1691.282 us; speedup vs baseline: 1.8111x; 1.8111x over previous
//
#include <hip/hip_runtime.h>

#define N_FACES 50000
#define N_EDGES 800000
#define NB      16
#define HID     256
#define NOUT    512

// ---------- wave helpers ----------
__device__ __forceinline__ float wave_sum(float v) {
#pragma unroll
  for (int o = 32; o; o >>= 1) v += __shfl_xor(v, o, 64);
  return v;
}

// ---------- order-preserving float<->uint encoding (for atomicMax) ----------
__device__ __forceinline__ unsigned enc_ord(float v) {
  unsigned b = __float_as_uint(v);
  return (b & 0x80000000u) ? ~b : (b | 0x80000000u);
}
__device__ __forceinline__ float dec_ord(unsigned e) {
  unsigned b = (e & 0x80000000u) ? (e ^ 0x80000000u) : ~e;
  return __uint_as_float(b);
}

// ---------- CSR build ----------
__global__ void k_hist(const int* __restrict__ dst, int* __restrict__ cnt) {
  int e = blockIdx.x * blockDim.x + threadIdx.x;
  if (e < N_EDGES) atomicAdd(&cnt[dst[e]], 1);
}

__global__ void k_scan(const int* __restrict__ cnt, int* __restrict__ row_ptr) {
  __shared__ int sh[1024];
  __shared__ int carry;
  int t = threadIdx.x;
  if (t == 0) carry = 0;
  __syncthreads();
  for (int base = 0; base <= N_FACES; base += 1024) {
    int i = base + t;
    int v = (i < N_FACES) ? cnt[i] : 0;
    sh[t] = v;
    __syncthreads();
    for (int off = 1; off < 1024; off <<= 1) {
      int x = (t >= off) ? sh[t - off] : 0;
      __syncthreads();
      sh[t] += x;
      __syncthreads();
    }
    if (i <= N_FACES) row_ptr[i] = carry + sh[t] - v;  // exclusive
    __syncthreads();
    if (t == 1023) carry += sh[1023];
    __syncthreads();
  }
}

__global__ void k_scatter(const int* __restrict__ dst, const int* __restrict__ src,
                          const int* __restrict__ row_ptr,
                          int* __restrict__ fill, int* __restrict__ edge_ids,
                          int* __restrict__ csr_src) {
  int e = blockIdx.x * blockDim.x + threadIdx.x;
  if (e < N_EDGES) {
    int d = dst[e];
    int p = atomicAdd(&fill[d], 1);
    int pos = row_ptr[d] + p;
    edge_ids[pos] = e;
    csr_src[pos] = src[e];
  }
}

// ---------- encoders + mean aggregation (one wave per node) ----------
__global__ void k_encode(const float* __restrict__ xf, const float* __restrict__ xe,
                         const float* __restrict__ fW, const float* __restrict__ fB,
                         const float* __restrict__ fG, const float* __restrict__ fBe,
                         const float* __restrict__ eW, const float* __restrict__ eB,
                         const float* __restrict__ eG, const float* __restrict__ eBe,
                         const int* __restrict__ row_ptr, const int* __restrict__ eid,
                         float* __restrict__ h) {
  int lane = threadIdx.x & 63;
  int n = blockIdx.x * 4 + (threadIdx.x >> 6);
  if (n >= N_FACES) return;

  float x[7];
#pragma unroll
  for (int k = 0; k < 7; ++k) x[k] = xf[n * 7 + k];
  float y[4];
#pragma unroll
  for (int j = 0; j < 4; ++j) {
    int c = lane + 64 * j;
    float a = fB[c];
#pragma unroll
    for (int k = 0; k < 7; ++k) a += x[k] * fW[k * HID + c];
    y[j] = fmaxf(a, 0.f);
  }
  float s = y[0] + y[1] + y[2] + y[3];
  float s2 = y[0] * y[0] + y[1] * y[1] + y[2] * y[2] + y[3] * y[3];
  s = wave_sum(s); s2 = wave_sum(s2);
  float mu = s * (1.f / HID);
  float rs = rsqrtf(fmaxf(s2 * (1.f / HID) - mu * mu, 0.f) + 1e-5f);
  float hv[4];
#pragma unroll
  for (int j = 0; j < 4; ++j) {
    int c = lane + 64 * j;
    hv[j] = (y[j] - mu) * rs * fG[c] + fBe[c];
  }

  int e0 = row_ptr[n], e1 = row_ptr[n + 1];
  float acc[4] = {0.f, 0.f, 0.f, 0.f};
  for (int t = e0; t < e1; ++t) {
    int e = eid[t];
    float z[6];
#pragma unroll
    for (int k = 0; k < 6; ++k) z[k] = xe[e * 6 + k];
    float w[4];
#pragma unroll
    for (int j = 0; j < 4; ++j) {
      int c = lane + 64 * j;
      float a = eB[c];
#pragma unroll
      for (int k = 0; k < 6; ++k) a += z[k] * eW[k * HID + c];
      w[j] = fmaxf(a, 0.f);
    }
    float t1 = w[0] + w[1] + w[2] + w[3];
    float t2 = w[0] * w[0] + w[1] * w[1] + w[2] * w[2] + w[3] * w[3];
    t1 = wave_sum(t1); t2 = wave_sum(t2);
    float mu2 = t1 * (1.f / HID);
    float rs2 = rsqrtf(fmaxf(t2 * (1.f / HID) - mu2 * mu2, 0.f) + 1e-5f);
#pragma unroll
    for (int j = 0; j < 4; ++j) {
      int c = lane + 64 * j;
      acc[j] += (w[j] - mu2) * rs2 * eG[c] + eBe[c];
    }
  }
  float inv = (e1 > e0) ? 1.f / (float)(e1 - e0) : 0.f;
#pragma unroll
  for (int j = 0; j < 4; ++j) h[(size_t)n * HID + lane + 64 * j] = hv[j] + acc[j] * inv;
}

// ---------- f = h @ W  (16 nodes per block, 256 threads) ----------
#define GM 16
__global__ void k_gemm256(const float* __restrict__ h, const float* __restrict__ W,
                          float* __restrict__ f) {
  __shared__ float hs[GM][HID];
  int n0 = blockIdx.x * GM;
  int c = threadIdx.x;
#pragma unroll
  for (int m = 0; m < GM; ++m) hs[m][c] = h[(size_t)(n0 + m) * HID + c];
  __syncthreads();
  float acc[GM];
#pragma unroll
  for (int m = 0; m < GM; ++m) acc[m] = 0.f;
  for (int k = 0; k < HID; ++k) {
    float w = W[k * HID + c];
#pragma unroll
    for (int m = 0; m < GM; ++m) acc[m] += hs[m][k] * w;
  }
#pragma unroll
  for (int m = 0; m < GM; ++m) f[(size_t)(n0 + m) * HID + c] = acc[m];
}

// ---------- el/er (one wave per node) ----------
__global__ void k_elr(const float* __restrict__ f, const float* __restrict__ al,
                      const float* __restrict__ ar, float* __restrict__ el,
                      float* __restrict__ er) {
  int lane = threadIdx.x & 63;
  int n = blockIdx.x * 4 + (threadIdx.x >> 6);
  if (n >= N_FACES) return;
  float4 v = reinterpret_cast<const float4*>(f)[(size_t)n * 64 + lane];
  float4 a = reinterpret_cast<const float4*>(al)[lane];
  float4 b = reinterpret_cast<const float4*>(ar)[lane];
  float pl = v.x * a.x + v.y * a.y + v.z * a.z + v.w * a.w;
  float pr = v.x * b.x + v.y * b.y + v.z * b.z + v.w * b.w;
#pragma unroll
  for (int o = 1; o < 16; o <<= 1) {
    pl += __shfl_xor(pl, o, 64);
    pr += __shfl_xor(pr, o, 64);
  }
  if ((lane & 15) == 0) {
    el[n * 4 + (lane >> 4)] = pl;
    er[n * 4 + (lane >> 4)] = pr;
  }
}

// ---------- GAT: 2 edge passes (max, then fused expsum+weighted gather) ----------
__global__ void k_gat(const float* __restrict__ f, const float* __restrict__ el,
                      const float* __restrict__ er, const int* __restrict__ row_ptr,
                      const int* __restrict__ csrc,
                      const float* __restrict__ bias, const float* __restrict__ g,
                      const float* __restrict__ be, float* __restrict__ h) {
  int lane = threadIdx.x & 63;
  int n = blockIdx.x * 4 + (threadIdx.x >> 6);
  if (n >= N_FACES) return;
  int e0 = row_ptr[n], e1 = row_ptr[n + 1];
  float4 ern = reinterpret_cast<const float4*>(er)[n];

  // pass 1: per-head max
  float m0 = -1e30f, m1 = -1e30f, m2 = -1e30f, m3 = -1e30f;
  for (int t = e0; t < e1; ++t) {
    int s = csrc[t];
    float4 e4 = reinterpret_cast<const float4*>(el)[s];
    float w;
    w = e4.x + ern.x; w = w > 0.f ? w : 0.2f * w; m0 = fmaxf(m0, w);
    w = e4.y + ern.y; w = w > 0.f ? w : 0.2f * w; m1 = fmaxf(m1, w);
    w = e4.z + ern.z; w = w > 0.f ? w : 0.2f * w; m2 = fmaxf(m2, w);
    w = e4.w + ern.w; w = w > 0.f ? w : 0.2f * w; m3 = fmaxf(m3, w);
  }

  // pass 2: fused unnormalized weighted gather + exp-sum
  float s0 = 0.f, s1 = 0.f, s2 = 0.f, s3 = 0.f;
  float a0 = 0.f, a1 = 0.f, a2 = 0.f, a3 = 0.f;
  for (int t = e0; t < e1; ++t) {
    int s = csrc[t];
    float4 e4 = reinterpret_cast<const float4*>(el)[s];
    float w, p;
    const float* fr = f + (size_t)s * HID;
    w = e4.x + ern.x; w = w > 0.f ? w : 0.2f * w; p = __expf(w - m0); s0 += p; a0 += fr[lane]       * p;
    w = e4.y + ern.y; w = w > 0.f ? w : 0.2f * w; p = __expf(w - m1); s1 += p; a1 += fr[lane + 64]  * p;
    w = e4.z + ern.z; w = w > 0.f ? w : 0.2f * w; p = __expf(w - m2); s2 += p; a2 += fr[lane + 128] * p;
    w = e4.w + ern.w; w = w > 0.f ? w : 0.2f * w; p = __expf(w - m3); s3 += p; a3 += fr[lane + 192] * p;
  }
  a0 *= (s0 > 0.f ? 1.f / s0 : 0.f);
  a1 *= (s1 > 0.f ? 1.f / s1 : 0.f);
  a2 *= (s2 > 0.f ? 1.f / s2 : 0.f);
  a3 *= (s3 > 0.f ? 1.f / s3 : 0.f);

  float y0 = fmaxf(a0 + bias[lane], 0.f);
  float y1 = fmaxf(a1 + bias[lane + 64], 0.f);
  float y2 = fmaxf(a2 + bias[lane + 128], 0.f);
  float y3 = fmaxf(a3 + bias[lane + 192], 0.f);
  float s = y0 + y1 + y2 + y3;
  float q = y0 * y0 + y1 * y1 + y2 * y2 + y3 * y3;
  s = wave_sum(s); q = wave_sum(q);
  float mu = s * (1.f / HID);
  float rs = rsqrtf(fmaxf(q * (1.f / HID) - mu * mu, 0.f) + 1e-5f);
  size_t base = (size_t)n * HID;
  h[base + lane]       = (y0 - mu) * rs * g[lane]       + be[lane];
  h[base + lane + 64]  = (y1 - mu) * rs * g[lane + 64]  + be[lane + 64];
  h[base + lane + 128] = (y2 - mu) * rs * g[lane + 128] + be[lane + 128];
  h[base + lane + 192] = (y3 - mu) * rs * g[lane + 192] + be[lane + 192];
}

// ---------- gate scores ----------
__global__ void k_gate(const float* __restrict__ h, const float* __restrict__ gw,
                       const float* __restrict__ gb, float* __restrict__ gate) {
  int lane = threadIdx.x & 63;
  int n = blockIdx.x * 4 + (threadIdx.x >> 6);
  if (n >= N_FACES) return;
  float4 v = reinterpret_cast<const float4*>(h)[(size_t)n * 64 + lane];
  float4 w = reinterpret_cast<const float4*>(gw)[lane];
  float p = v.x * w.x + v.y * w.y + v.z * w.z + v.w * w.w;
  p = wave_sum(p);
  if (lane == 0) gate[n] = p + gb[0];
}

// ---------- per-graph max of gate (order-encoded atomicMax) ----------
__global__ void k_gmax(const float* __restrict__ gate, const int* __restrict__ gid,
                       unsigned* __restrict__ gmax_u) {
  int n = blockIdx.x * blockDim.x + threadIdx.x;
  if (n < N_FACES) atomicMax(&gmax_u[gid[n]], enc_ord(gate[n]));
}

// ---------- parallel weighted pooling (unnormalized) ----------
#define PCHUNK 125
__global__ void k_psum(const float* __restrict__ h, const float* __restrict__ gate,
                       const int* __restrict__ gid, const unsigned* __restrict__ gmax_u,
                       float* __restrict__ praw, float* __restrict__ gs) {
  int t = threadIdx.x;
  int n0 = blockIdx.x * PCHUNK;
  int n1 = n0 + PCHUNK;
  if (n1 > N_FACES) n1 = N_FACES;
  if (n0 >= N_FACES) return;
  int cur = gid[n0];
  float gm = dec_ord(gmax_u[cur]);
  float acc = 0.f, wsum = 0.f;
  for (int n = n0; n < n1; ++n) {
    int g = gid[n];
    if (g != cur) {
      atomicAdd(&praw[cur * HID + t], acc);
      if (t == 0) atomicAdd(&gs[cur], wsum);
      acc = 0.f; wsum = 0.f; cur = g; gm = dec_ord(gmax_u[cur]);
    }
    float w = __expf(gate[n] - gm);
    acc += w * h[(size_t)n * HID + t];
    wsum += w;
  }
  atomicAdd(&praw[cur * HID + t], acc);
  if (t == 0) atomicAdd(&gs[cur], wsum);
}

__global__ void k_poolnorm(const float* __restrict__ praw, const float* __restrict__ gs,
                           float* __restrict__ pooled) {
  int b = blockIdx.x, c = threadIdx.x;
  pooled[b * HID + c] = praw[b * HID + c] / gs[b];
}

// ---------- output projection + LN ----------
__global__ void k_out(const float* __restrict__ pooled, const float* __restrict__ oW,
                      const float* __restrict__ oB, const float* __restrict__ oG,
                      const float* __restrict__ oBe, float* __restrict__ feat) {
  int b = blockIdx.x;
  int o = threadIdx.x;  // 512 threads
  int lane = o & 63, wid = o >> 6;
  __shared__ float p[HID];
  __shared__ float partS[8], partQ[8];
  __shared__ float shMu, shRs;
  if (o < HID) p[o] = pooled[b * HID + o];
  __syncthreads();
  float a = oB[o];
  for (int k = 0; k < HID; ++k) a += p[k] * oW[k * NOUT + o];
  float y = fmaxf(a, 0.f);
  float s = wave_sum(y), q = wave_sum(y * y);
  if (lane == 0) { partS[wid] = s; partQ[wid] = q; }
  __syncthreads();
  if (o == 0) {
    float S = 0.f, Q = 0.f;
#pragma unroll
    for (int i = 0; i < 8; ++i) { S += partS[i]; Q += partQ[i]; }
    float mu = S * (1.f / NOUT);
    shMu = mu;
    shRs = rsqrtf(fmaxf(Q * (1.f / NOUT) - mu * mu, 0.f) + 1e-5f);
  }
  __syncthreads();
  feat[b * NOUT + o] = (y - shMu) * shRs * oG[o] + oBe[o];
}

extern "C" void kernel_launch(void* const* d_in, const int* in_sizes, int n_in,
                              void* d_out, int out_size, void* d_ws, size_t ws_size,
                              hipStream_t stream) {
  (void)in_sizes; (void)n_in; (void)out_size; (void)ws_size;
  const float* x_face    = (const float*)d_in[0];
  const float* x_edge    = (const float*)d_in[1];
  const float* face_W    = (const float*)d_in[2];
  const float* face_b    = (const float*)d_in[3];
  const float* face_g    = (const float*)d_in[4];
  const float* face_beta = (const float*)d_in[5];
  const float* edge_W    = (const float*)d_in[6];
  const float* edge_b    = (const float*)d_in[7];
  const float* edge_g    = (const float*)d_in[8];
  const float* edge_beta = (const float*)d_in[9];
  const float* g0_W      = (const float*)d_in[10];
  const float* g0_al     = (const float*)d_in[11];
  const float* g0_ar     = (const float*)d_in[12];
  const float* g0_bias   = (const float*)d_in[13];
  const float* g0_g      = (const float*)d_in[14];
  const float* g0_beta   = (const float*)d_in[15];
  const float* g1_W      = (const float*)d_in[16];
  const float* g1_al     = (const float*)d_in[17];
  const float* g1_ar     = (const float*)d_in[18];
  const float* g1_bias   = (const float*)d_in[19];
  const float* g1_g      = (const float*)d_in[20];
  const float* g1_beta   = (const float*)d_in[21];
  const float* gate_W    = (const float*)d_in[22];
  const float* gate_b    = (const float*)d_in[23];
  const float* out_W     = (const float*)d_in[24];
  const float* out_b     = (const float*)d_in[25];
  const float* out_g     = (const float*)d_in[26];
  const float* out_beta  = (const float*)d_in[27];
  const int*   src       = (const int*)d_in[28];
  const int*   dst       = (const int*)d_in[29];
  const int*   gid       = (const int*)d_in[30];

  char* ws = (char*)d_ws;
  size_t off = 0;
  auto take = [&](size_t bytes) -> char* {
    char* pp = ws + off;
    off += (bytes + 255) & ~(size_t)255;
    return pp;
  };
  int*      cnt      = (int*)take((size_t)N_FACES * 4);
  int*      fill     = (int*)take((size_t)N_FACES * 4);
  int*      row_ptr  = (int*)take((size_t)(N_FACES + 1) * 4);
  int*      edge_ids = (int*)take((size_t)N_EDGES * 4);
  int*      csr_src  = (int*)take((size_t)N_EDGES * 4);
  unsigned* gmax_u   = (unsigned*)take(64);
  float*    gs       = (float*)take(64);
  float*    praw     = (float*)take((size_t)NB * HID * 4);
  float*    el       = (float*)take((size_t)N_FACES * 4 * 4);
  float*    er       = (float*)take((size_t)N_FACES * 4 * 4);
  float*    gate     = (float*)take((size_t)N_FACES * 4);
  float*    f        = (float*)take((size_t)N_FACES * HID * 4);

  float* outp   = (float*)d_out;
  float* feat   = outp;
  float* h      = outp + NB * NOUT;
  float* pooled = outp + NB * NOUT + (size_t)N_FACES * HID;

  hipMemsetAsync(cnt, 0, (size_t)N_FACES * 4, stream);
  hipMemsetAsync(fill, 0, (size_t)N_FACES * 4, stream);
  hipMemsetAsync(gmax_u, 0, 64, stream);
  hipMemsetAsync(gs, 0, 64, stream);
  hipMemsetAsync(praw, 0, (size_t)NB * HID * 4, stream);

  k_hist<<<(N_EDGES + 255) / 256, 256, 0, stream>>>(dst, cnt);
  k_scan<<<1, 1024, 0, stream>>>(cnt, row_ptr);
  k_scatter<<<(N_EDGES + 255) / 256, 256, 0, stream>>>(dst, src, row_ptr, fill,
                                                       edge_ids, csr_src);

  k_encode<<<N_FACES / 4, 256, 0, stream>>>(x_face, x_edge, face_W, face_b, face_g, face_beta,
                                            edge_W, edge_b, edge_g, edge_beta,
                                            row_ptr, edge_ids, h);
  // GAT layer 0
  k_gemm256<<<N_FACES / GM, 256, 0, stream>>>(h, g0_W, f);
  k_elr<<<N_FACES / 4, 256, 0, stream>>>(f, g0_al, g0_ar, el, er);
  k_gat<<<N_FACES / 4, 256, 0, stream>>>(f, el, er, row_ptr, csr_src,
                                         g0_bias, g0_g, g0_beta, h);
  // GAT layer 1
  k_gemm256<<<N_FACES / GM, 256, 0, stream>>>(h, g1_W, f);
  k_elr<<<N_FACES / 4, 256, 0, stream>>>(f, g1_al, g1_ar, el, er);
  k_gat<<<N_FACES / 4, 256, 0, stream>>>(f, el, er, row_ptr, csr_src,
                                         g1_bias, g1_g, g1_beta, h);
  // pooling + output head
  k_gate<<<N_FACES / 4, 256, 0, stream>>>(h, gate_W, gate_b, gate);
  k_gmax<<<(N_FACES + 255) / 256, 256, 0, stream>>>(gate, gid, gmax_u);
  k_psum<<<(N_FACES + PCHUNK - 1) / PCHUNK, 256, 0, stream>>>(h, gate, gid, gmax_u, praw, gs);
  k_poolnorm<<<NB, HID, 0, stream>>>(praw, gs, pooled);
  k_out<<<NB, NOUT, 0, stream>>>(pooled, out_W, out_b, out_g, out_beta, feat);
}

// Round 3
// 1007.835 us; speedup vs baseline: 3.0392x; 1.6781x over previous
//
#include <hip/hip_runtime.h>

#define N_FACES 50000
#define N_EDGES 800000
#define NB      16
#define HID     256
#define NOUT    512

// ---------- wave helpers ----------
__device__ __forceinline__ float wave_sum(float v) {
#pragma unroll
  for (int o = 32; o; o >>= 1) v += __shfl_xor(v, o, 64);
  return v;
}

// ---------- order-preserving float<->uint encoding (for atomicMax) ----------
__device__ __forceinline__ unsigned enc_ord(float v) {
  unsigned b = __float_as_uint(v);
  return (b & 0x80000000u) ? ~b : (b | 0x80000000u);
}
__device__ __forceinline__ float dec_ord(unsigned e) {
  unsigned b = (e & 0x80000000u) ? (e ^ 0x80000000u) : ~e;
  return __uint_as_float(b);
}

// ---------- CSR build ----------
__global__ void k_hist(const int* __restrict__ dst, int* __restrict__ cnt) {
  int e = blockIdx.x * blockDim.x + threadIdx.x;
  if (e < N_EDGES) atomicAdd(&cnt[dst[e]], 1);
}

__global__ void k_scan(const int* __restrict__ cnt, int* __restrict__ row_ptr) {
  __shared__ int sh[1024];
  __shared__ int carry;
  int t = threadIdx.x;
  if (t == 0) carry = 0;
  __syncthreads();
  for (int base = 0; base <= N_FACES; base += 1024) {
    int i = base + t;
    int v = (i < N_FACES) ? cnt[i] : 0;
    sh[t] = v;
    __syncthreads();
    for (int off = 1; off < 1024; off <<= 1) {
      int x = (t >= off) ? sh[t - off] : 0;
      __syncthreads();
      sh[t] += x;
      __syncthreads();
    }
    if (i <= N_FACES) row_ptr[i] = carry + sh[t] - v;  // exclusive
    __syncthreads();
    if (t == 1023) carry += sh[1023];
    __syncthreads();
  }
}

__global__ void k_scatter(const int* __restrict__ dst, const int* __restrict__ src,
                          const int* __restrict__ row_ptr,
                          int* __restrict__ fill, int* __restrict__ edge_ids,
                          int* __restrict__ csr_src) {
  int e = blockIdx.x * blockDim.x + threadIdx.x;
  if (e < N_EDGES) {
    int d = dst[e];
    int p = atomicAdd(&fill[d], 1);
    int pos = row_ptr[d] + p;
    edge_ids[pos] = e;
    csr_src[pos] = src[e];
  }
}

// ---------- encoders + mean aggregation (one wave per node) ----------
__global__ void k_encode(const float* __restrict__ xf, const float* __restrict__ xe,
                         const float* __restrict__ fW, const float* __restrict__ fB,
                         const float* __restrict__ fG, const float* __restrict__ fBe,
                         const float* __restrict__ eW, const float* __restrict__ eB,
                         const float* __restrict__ eG, const float* __restrict__ eBe,
                         const int* __restrict__ row_ptr, const int* __restrict__ eid,
                         float* __restrict__ h) {
  int lane = threadIdx.x & 63;
  int n = blockIdx.x * 4 + (threadIdx.x >> 6);
  if (n >= N_FACES) return;

  float x[7];
#pragma unroll
  for (int k = 0; k < 7; ++k) x[k] = xf[n * 7 + k];
  float y[4];
#pragma unroll
  for (int j = 0; j < 4; ++j) {
    int c = lane + 64 * j;
    float a = fB[c];
#pragma unroll
    for (int k = 0; k < 7; ++k) a += x[k] * fW[k * HID + c];
    y[j] = fmaxf(a, 0.f);
  }
  float s = y[0] + y[1] + y[2] + y[3];
  float s2 = y[0] * y[0] + y[1] * y[1] + y[2] * y[2] + y[3] * y[3];
  s = wave_sum(s); s2 = wave_sum(s2);
  float mu = s * (1.f / HID);
  float rs = rsqrtf(fmaxf(s2 * (1.f / HID) - mu * mu, 0.f) + 1e-5f);
  float hv[4];
#pragma unroll
  for (int j = 0; j < 4; ++j) {
    int c = lane + 64 * j;
    hv[j] = (y[j] - mu) * rs * fG[c] + fBe[c];
  }

  int e0 = row_ptr[n], e1 = row_ptr[n + 1];
  float acc[4] = {0.f, 0.f, 0.f, 0.f};
  for (int t = e0; t < e1; ++t) {
    int e = eid[t];
    float z[6];
#pragma unroll
    for (int k = 0; k < 6; ++k) z[k] = xe[e * 6 + k];
    float w[4];
#pragma unroll
    for (int j = 0; j < 4; ++j) {
      int c = lane + 64 * j;
      float a = eB[c];
#pragma unroll
      for (int k = 0; k < 6; ++k) a += z[k] * eW[k * HID + c];
      w[j] = fmaxf(a, 0.f);
    }
    float t1 = w[0] + w[1] + w[2] + w[3];
    float t2 = w[0] * w[0] + w[1] * w[1] + w[2] * w[2] + w[3] * w[3];
    t1 = wave_sum(t1); t2 = wave_sum(t2);
    float mu2 = t1 * (1.f / HID);
    float rs2 = rsqrtf(fmaxf(t2 * (1.f / HID) - mu2 * mu2, 0.f) + 1e-5f);
#pragma unroll
    for (int j = 0; j < 4; ++j) {
      int c = lane + 64 * j;
      acc[j] += (w[j] - mu2) * rs2 * eG[c] + eBe[c];
    }
  }
  float inv = (e1 > e0) ? 1.f / (float)(e1 - e0) : 0.f;
#pragma unroll
  for (int j = 0; j < 4; ++j) h[(size_t)n * HID + lane + 64 * j] = hv[j] + acc[j] * inv;
}

// ---------- f = h @ W  (16 nodes per block, 256 threads) ----------
#define GM 16
__global__ void k_gemm256(const float* __restrict__ h, const float* __restrict__ W,
                          float* __restrict__ f) {
  __shared__ float hs[GM][HID];
  int n0 = blockIdx.x * GM;
  int c = threadIdx.x;
#pragma unroll
  for (int m = 0; m < GM; ++m) hs[m][c] = h[(size_t)(n0 + m) * HID + c];
  __syncthreads();
  float acc[GM];
#pragma unroll
  for (int m = 0; m < GM; ++m) acc[m] = 0.f;
  for (int k = 0; k < HID; ++k) {
    float w = W[k * HID + c];
#pragma unroll
    for (int m = 0; m < GM; ++m) acc[m] += hs[m][k] * w;
  }
#pragma unroll
  for (int m = 0; m < GM; ++m) f[(size_t)(n0 + m) * HID + c] = acc[m];
}

// ---------- el/er (one wave per node) ----------
__global__ void k_elr(const float* __restrict__ f, const float* __restrict__ al,
                      const float* __restrict__ ar, float* __restrict__ el,
                      float* __restrict__ er) {
  int lane = threadIdx.x & 63;
  int n = blockIdx.x * 4 + (threadIdx.x >> 6);
  if (n >= N_FACES) return;
  float4 v = reinterpret_cast<const float4*>(f)[(size_t)n * 64 + lane];
  float4 a = reinterpret_cast<const float4*>(al)[lane];
  float4 b = reinterpret_cast<const float4*>(ar)[lane];
  float pl = v.x * a.x + v.y * a.y + v.z * a.z + v.w * a.w;
  float pr = v.x * b.x + v.y * b.y + v.z * b.z + v.w * b.w;
#pragma unroll
  for (int o = 1; o < 16; o <<= 1) {
    pl += __shfl_xor(pl, o, 64);
    pr += __shfl_xor(pr, o, 64);
  }
  if ((lane & 15) == 0) {
    el[n * 4 + (lane >> 4)] = pl;
    er[n * 4 + (lane >> 4)] = pr;
  }
}

// ---------- GAT: single fused edge pass (softmax is shift-invariant; scores are
// O(1) by LN scale analysis, so exp without max-shift cannot overflow) ----------
__global__ void k_gat(const float* __restrict__ f, const float* __restrict__ el,
                      const float* __restrict__ er, const int* __restrict__ row_ptr,
                      const int* __restrict__ csrc,
                      const float* __restrict__ bias, const float* __restrict__ g,
                      const float* __restrict__ be, float* __restrict__ h) {
  int lane = threadIdx.x & 63;
  int n = blockIdx.x * 4 + (threadIdx.x >> 6);
  if (n >= N_FACES) return;
  int e0 = row_ptr[n], e1 = row_ptr[n + 1];
  float4 ern = reinterpret_cast<const float4*>(er)[n];

  float s0 = 0.f, s1 = 0.f, s2 = 0.f, s3 = 0.f;
  float a0 = 0.f, a1 = 0.f, a2 = 0.f, a3 = 0.f;
  for (int t = e0; t < e1; ++t) {
    int s = csrc[t];
    float4 e4 = reinterpret_cast<const float4*>(el)[s];
    float w, p;
    const float* fr = f + (size_t)s * HID;
    w = e4.x + ern.x; w = w > 0.f ? w : 0.2f * w; p = __expf(w); s0 += p; a0 += fr[lane]       * p;
    w = e4.y + ern.y; w = w > 0.f ? w : 0.2f * w; p = __expf(w); s1 += p; a1 += fr[lane + 64]  * p;
    w = e4.z + ern.z; w = w > 0.f ? w : 0.2f * w; p = __expf(w); s2 += p; a2 += fr[lane + 128] * p;
    w = e4.w + ern.w; w = w > 0.f ? w : 0.2f * w; p = __expf(w); s3 += p; a3 += fr[lane + 192] * p;
  }
  a0 *= (s0 > 0.f ? 1.f / s0 : 0.f);
  a1 *= (s1 > 0.f ? 1.f / s1 : 0.f);
  a2 *= (s2 > 0.f ? 1.f / s2 : 0.f);
  a3 *= (s3 > 0.f ? 1.f / s3 : 0.f);

  float y0 = fmaxf(a0 + bias[lane], 0.f);
  float y1 = fmaxf(a1 + bias[lane + 64], 0.f);
  float y2 = fmaxf(a2 + bias[lane + 128], 0.f);
  float y3 = fmaxf(a3 + bias[lane + 192], 0.f);
  float s = y0 + y1 + y2 + y3;
  float q = y0 * y0 + y1 * y1 + y2 * y2 + y3 * y3;
  s = wave_sum(s); q = wave_sum(q);
  float mu = s * (1.f / HID);
  float rs = rsqrtf(fmaxf(q * (1.f / HID) - mu * mu, 0.f) + 1e-5f);
  size_t base = (size_t)n * HID;
  h[base + lane]       = (y0 - mu) * rs * g[lane]       + be[lane];
  h[base + lane + 64]  = (y1 - mu) * rs * g[lane + 64]  + be[lane + 64];
  h[base + lane + 128] = (y2 - mu) * rs * g[lane + 128] + be[lane + 128];
  h[base + lane + 192] = (y3 - mu) * rs * g[lane + 192] + be[lane + 192];
}

// ---------- gate scores ----------
__global__ void k_gate(const float* __restrict__ h, const float* __restrict__ gw,
                       const float* __restrict__ gb, float* __restrict__ gate) {
  int lane = threadIdx.x & 63;
  int n = blockIdx.x * 4 + (threadIdx.x >> 6);
  if (n >= N_FACES) return;
  float4 v = reinterpret_cast<const float4*>(h)[(size_t)n * 64 + lane];
  float4 w = reinterpret_cast<const float4*>(gw)[lane];
  float p = v.x * w.x + v.y * w.y + v.z * w.z + v.w * w.w;
  p = wave_sum(p);
  if (lane == 0) gate[n] = p + gb[0];
}

// ---------- per-graph max of gate: LDS pre-reduction, then global atomics ----------
__global__ void k_gmax(const float* __restrict__ gate, const int* __restrict__ gid,
                       unsigned* __restrict__ gmax_u) {
  __shared__ unsigned sm[NB];
  int t = threadIdx.x;
  if (t < NB) sm[t] = 0u;
  __syncthreads();
  int n = blockIdx.x * blockDim.x + t;
  if (n < N_FACES) atomicMax(&sm[gid[n]], enc_ord(gate[n]));
  __syncthreads();
  if (t < NB && sm[t] != 0u) atomicMax(&gmax_u[t], sm[t]);
}

// ---------- parallel weighted pooling (unnormalized) ----------
#define PCHUNK 125
__global__ void k_psum(const float* __restrict__ h, const float* __restrict__ gate,
                       const int* __restrict__ gid, const unsigned* __restrict__ gmax_u,
                       float* __restrict__ praw, float* __restrict__ gs) {
  int t = threadIdx.x;
  int n0 = blockIdx.x * PCHUNK;
  int n1 = n0 + PCHUNK;
  if (n1 > N_FACES) n1 = N_FACES;
  if (n0 >= N_FACES) return;
  int cur = gid[n0];
  float gm = dec_ord(gmax_u[cur]);
  float acc = 0.f, wsum = 0.f;
  for (int n = n0; n < n1; ++n) {
    int g = gid[n];
    if (g != cur) {
      atomicAdd(&praw[cur * HID + t], acc);
      if (t == 0) atomicAdd(&gs[cur], wsum);
      acc = 0.f; wsum = 0.f; cur = g; gm = dec_ord(gmax_u[cur]);
    }
    float w = __expf(gate[n] - gm);
    acc += w * h[(size_t)n * HID + t];
    wsum += w;
  }
  atomicAdd(&praw[cur * HID + t], acc);
  if (t == 0) atomicAdd(&gs[cur], wsum);
}

__global__ void k_poolnorm(const float* __restrict__ praw, const float* __restrict__ gs,
                           float* __restrict__ pooled) {
  int b = blockIdx.x, c = threadIdx.x;
  pooled[b * HID + c] = praw[b * HID + c] / gs[b];
}

// ---------- output projection + LN ----------
__global__ void k_out(const float* __restrict__ pooled, const float* __restrict__ oW,
                      const float* __restrict__ oB, const float* __restrict__ oG,
                      const float* __restrict__ oBe, float* __restrict__ feat) {
  int b = blockIdx.x;
  int o = threadIdx.x;  // 512 threads
  int lane = o & 63, wid = o >> 6;
  __shared__ float p[HID];
  __shared__ float partS[8], partQ[8];
  __shared__ float shMu, shRs;
  if (o < HID) p[o] = pooled[b * HID + o];
  __syncthreads();
  float a = oB[o];
  for (int k = 0; k < HID; ++k) a += p[k] * oW[k * NOUT + o];
  float y = fmaxf(a, 0.f);
  float s = wave_sum(y), q = wave_sum(y * y);
  if (lane == 0) { partS[wid] = s; partQ[wid] = q; }
  __syncthreads();
  if (o == 0) {
    float S = 0.f, Q = 0.f;
#pragma unroll
    for (int i = 0; i < 8; ++i) { S += partS[i]; Q += partQ[i]; }
    float mu = S * (1.f / NOUT);
    shMu = mu;
    shRs = rsqrtf(fmaxf(Q * (1.f / NOUT) - mu * mu, 0.f) + 1e-5f);
  }
  __syncthreads();
  feat[b * NOUT + o] = (y - shMu) * shRs * oG[o] + oBe[o];
}

extern "C" void kernel_launch(void* const* d_in, const int* in_sizes, int n_in,
                              void* d_out, int out_size, void* d_ws, size_t ws_size,
                              hipStream_t stream) {
  (void)in_sizes; (void)n_in; (void)out_size; (void)ws_size;
  const float* x_face    = (const float*)d_in[0];
  const float* x_edge    = (const float*)d_in[1];
  const float* face_W    = (const float*)d_in[2];
  const float* face_b    = (const float*)d_in[3];
  const float* face_g    = (const float*)d_in[4];
  const float* face_beta = (const float*)d_in[5];
  const float* edge_W    = (const float*)d_in[6];
  const float* edge_b    = (const float*)d_in[7];
  const float* edge_g    = (const float*)d_in[8];
  const float* edge_beta = (const float*)d_in[9];
  const float* g0_W      = (const float*)d_in[10];
  const float* g0_al     = (const float*)d_in[11];
  const float* g0_ar     = (const float*)d_in[12];
  const float* g0_bias   = (const float*)d_in[13];
  const float* g0_g      = (const float*)d_in[14];
  const float* g0_beta   = (const float*)d_in[15];
  const float* g1_W      = (const float*)d_in[16];
  const float* g1_al     = (const float*)d_in[17];
  const float* g1_ar     = (const float*)d_in[18];
  const float* g1_bias   = (const float*)d_in[19];
  const float* g1_g      = (const float*)d_in[20];
  const float* g1_beta   = (const float*)d_in[21];
  const float* gate_W    = (const float*)d_in[22];
  const float* gate_b    = (const float*)d_in[23];
  const float* out_W     = (const float*)d_in[24];
  const float* out_b     = (const float*)d_in[25];
  const float* out_g     = (const float*)d_in[26];
  const float* out_beta  = (const float*)d_in[27];
  const int*   src       = (const int*)d_in[28];
  const int*   dst       = (const int*)d_in[29];
  const int*   gid       = (const int*)d_in[30];

  char* ws = (char*)d_ws;
  size_t off = 0;
  auto take = [&](size_t bytes) -> char* {
    char* pp = ws + off;
    off += (bytes + 255) & ~(size_t)255;
    return pp;
  };
  int*      cnt      = (int*)take((size_t)N_FACES * 4);
  int*      fill     = (int*)take((size_t)N_FACES * 4);
  int*      row_ptr  = (int*)take((size_t)(N_FACES + 1) * 4);
  int*      edge_ids = (int*)take((size_t)N_EDGES * 4);
  int*      csr_src  = (int*)take((size_t)N_EDGES * 4);
  unsigned* gmax_u   = (unsigned*)take(64);
  float*    gs       = (float*)take(64);
  float*    praw     = (float*)take((size_t)NB * HID * 4);
  float*    el       = (float*)take((size_t)N_FACES * 4 * 4);
  float*    er       = (float*)take((size_t)N_FACES * 4 * 4);
  float*    gate     = (float*)take((size_t)N_FACES * 4);
  float*    f        = (float*)take((size_t)N_FACES * HID * 4);

  float* outp   = (float*)d_out;
  float* feat   = outp;
  float* h      = outp + NB * NOUT;
  float* pooled = outp + NB * NOUT + (size_t)N_FACES * HID;

  hipMemsetAsync(cnt, 0, (size_t)N_FACES * 4, stream);
  hipMemsetAsync(fill, 0, (size_t)N_FACES * 4, stream);
  hipMemsetAsync(gmax_u, 0, 64, stream);
  hipMemsetAsync(gs, 0, 64, stream);
  hipMemsetAsync(praw, 0, (size_t)NB * HID * 4, stream);

  k_hist<<<(N_EDGES + 255) / 256, 256, 0, stream>>>(dst, cnt);
  k_scan<<<1, 1024, 0, stream>>>(cnt, row_ptr);
  k_scatter<<<(N_EDGES + 255) / 256, 256, 0, stream>>>(dst, src, row_ptr, fill,
                                                       edge_ids, csr_src);

  k_encode<<<N_FACES / 4, 256, 0, stream>>>(x_face, x_edge, face_W, face_b, face_g, face_beta,
                                            edge_W, edge_b, edge_g, edge_beta,
                                            row_ptr, edge_ids, h);
  // GAT layer 0
  k_gemm256<<<N_FACES / GM, 256, 0, stream>>>(h, g0_W, f);
  k_elr<<<N_FACES / 4, 256, 0, stream>>>(f, g0_al, g0_ar, el, er);
  k_gat<<<N_FACES / 4, 256, 0, stream>>>(f, el, er, row_ptr, csr_src,
                                         g0_bias, g0_g, g0_beta, h);
  // GAT layer 1
  k_gemm256<<<N_FACES / GM, 256, 0, stream>>>(h, g1_W, f);
  k_elr<<<N_FACES / 4, 256, 0, stream>>>(f, g1_al, g1_ar, el, er);
  k_gat<<<N_FACES / 4, 256, 0, stream>>>(f, el, er, row_ptr, csr_src,
                                         g1_bias, g1_g, g1_beta, h);
  // pooling + output head
  k_gate<<<N_FACES / 4, 256, 0, stream>>>(h, gate_W, gate_b, gate);
  k_gmax<<<(N_FACES + 255) / 256, 256, 0, stream>>>(gate, gid, gmax_u);
  k_psum<<<(N_FACES + PCHUNK - 1) / PCHUNK, 256, 0, stream>>>(h, gate, gid, gmax_u, praw, gs);
  k_poolnorm<<<NB, HID, 0, stream>>>(praw, gs, pooled);
  k_out<<<NB, NOUT, 0, stream>>>(pooled, out_W, out_b, out_g, out_beta, feat);
}

// Round 4
// 866.975 us; speedup vs baseline: 3.5330x; 1.1625x over previous
//
#include <hip/hip_runtime.h>

#define N_FACES 50000
#define N_EDGES 800000
#define NB      16
#define HID     256
#define NOUT    512
#define SCAN_B  1024
#define SCAN_NB ((N_FACES + SCAN_B - 1) / SCAN_B)

// ---------- wave helpers ----------
__device__ __forceinline__ float wave_sum(float v) {
#pragma unroll
  for (int o = 32; o; o >>= 1) v += __shfl_xor(v, o, 64);
  return v;
}

// ---------- order-preserving float<->uint encoding (for atomicMax) ----------
__device__ __forceinline__ unsigned enc_ord(float v) {
  unsigned b = __float_as_uint(v);
  return (b & 0x80000000u) ? ~b : (b | 0x80000000u);
}
__device__ __forceinline__ float dec_ord(unsigned e) {
  unsigned b = (e & 0x80000000u) ? (e ^ 0x80000000u) : ~e;
  return __uint_as_float(b);
}

// ---------- CSR build ----------
__global__ void k_hist(const int* __restrict__ dst, int* __restrict__ cnt) {
  int e = blockIdx.x * blockDim.x + threadIdx.x;
  if (e < N_EDGES) atomicAdd(&cnt[dst[e]], 1);
}

// 3-phase parallel exclusive scan of cnt[N_FACES] -> row_ptr[N_FACES+1]
__global__ void k_scan1(const int* __restrict__ cnt, int* __restrict__ bsum) {
  __shared__ int sh[SCAN_B];
  int i = blockIdx.x * SCAN_B + threadIdx.x;
  sh[threadIdx.x] = (i < N_FACES) ? cnt[i] : 0;
  __syncthreads();
  for (int off = SCAN_B / 2; off; off >>= 1) {
    if (threadIdx.x < off) sh[threadIdx.x] += sh[threadIdx.x + off];
    __syncthreads();
  }
  if (threadIdx.x == 0) bsum[blockIdx.x] = sh[0];
}

__global__ void k_scan2(int* __restrict__ bsum) {  // nb <= 64, one wave
  int t = threadIdx.x;
  int v = (t < SCAN_NB) ? bsum[t] : 0;
  int inc = v;
#pragma unroll
  for (int off = 1; off < 64; off <<= 1) {
    int u = __shfl_up(inc, off, 64);
    if (t >= off) inc += u;
  }
  if (t < SCAN_NB) bsum[t] = inc - v;  // exclusive
}

__global__ void k_scan3(const int* __restrict__ cnt, const int* __restrict__ bsum,
                        int* __restrict__ row_ptr) {
  __shared__ int sh[SCAN_B];
  int i = blockIdx.x * SCAN_B + threadIdx.x;
  int v = (i < N_FACES) ? cnt[i] : 0;
  sh[threadIdx.x] = v;
  __syncthreads();
  for (int off = 1; off < SCAN_B; off <<= 1) {
    int x = (threadIdx.x >= off) ? sh[threadIdx.x - off] : 0;
    __syncthreads();
    sh[threadIdx.x] += x;
    __syncthreads();
  }
  if (i < N_FACES) row_ptr[i] = bsum[blockIdx.x] + sh[threadIdx.x] - v;
  if (i == 0) row_ptr[N_FACES] = N_EDGES;
}

// scatter: edge features + src ids into CSR order (removes eid indirection)
__global__ void k_scatter(const int* __restrict__ dst, const int* __restrict__ src,
                          const float* __restrict__ xe, const int* __restrict__ row_ptr,
                          int* __restrict__ fill, float* __restrict__ csr_xe,
                          int* __restrict__ csr_src) {
  int e = blockIdx.x * blockDim.x + threadIdx.x;
  if (e < N_EDGES) {
    int d = dst[e];
    int p = atomicAdd(&fill[d], 1);
    int pos = row_ptr[d] + p;
    csr_src[pos] = src[e];
#pragma unroll
    for (int k = 0; k < 6; ++k) csr_xe[(size_t)pos * 6 + k] = xe[(size_t)e * 6 + k];
  }
}

// ---------- encoders + mean aggregation (one wave per node) ----------
__global__ void k_encode(const float* __restrict__ xf, const float* __restrict__ csr_xe,
                         const float* __restrict__ fW, const float* __restrict__ fB,
                         const float* __restrict__ fG, const float* __restrict__ fBe,
                         const float* __restrict__ eW, const float* __restrict__ eB,
                         const float* __restrict__ eG, const float* __restrict__ eBe,
                         const int* __restrict__ row_ptr, float* __restrict__ h) {
  int lane = threadIdx.x & 63;
  int n = blockIdx.x * 4 + (threadIdx.x >> 6);
  if (n >= N_FACES) return;

  // face encoder
  float x[7];
#pragma unroll
  for (int k = 0; k < 7; ++k) x[k] = xf[n * 7 + k];
  float y[4];
#pragma unroll
  for (int j = 0; j < 4; ++j) {
    int c = lane + 64 * j;
    float a = fB[c];
#pragma unroll
    for (int k = 0; k < 7; ++k) a += x[k] * fW[k * HID + c];
    y[j] = fmaxf(a, 0.f);
  }
  float s = y[0] + y[1] + y[2] + y[3];
  float s2 = y[0] * y[0] + y[1] * y[1] + y[2] * y[2] + y[3] * y[3];
  s = wave_sum(s); s2 = wave_sum(s2);
  float mu = s * (1.f / HID);
  float rs = rsqrtf(fmaxf(s2 * (1.f / HID) - mu * mu, 0.f) + 1e-5f);
  float hv[4];
#pragma unroll
  for (int j = 0; j < 4; ++j) {
    int c = lane + 64 * j;
    hv[j] = (y[j] - mu) * rs * fG[c] + fBe[c];
  }

  // hoist edge-encoder params into registers (loop-invariant)
  float ew[6][4], eb[4], eg[4], ebe[4];
#pragma unroll
  for (int j = 0; j < 4; ++j) {
    int c = lane + 64 * j;
    eb[j] = eB[c]; eg[j] = eG[c]; ebe[j] = eBe[c];
#pragma unroll
    for (int k = 0; k < 6; ++k) ew[k][j] = eW[k * HID + c];
  }

  int e0 = row_ptr[n], e1 = row_ptr[n + 1];
  float acc[4] = {0.f, 0.f, 0.f, 0.f};
  float zn[6];
  if (e0 < e1) {
#pragma unroll
    for (int k = 0; k < 6; ++k) zn[k] = csr_xe[(size_t)e0 * 6 + k];
  }
  for (int t = e0; t < e1; ++t) {
    float z[6];
#pragma unroll
    for (int k = 0; k < 6; ++k) z[k] = zn[k];
    if (t + 1 < e1) {
#pragma unroll
      for (int k = 0; k < 6; ++k) zn[k] = csr_xe[(size_t)(t + 1) * 6 + k];
    }
    float w[4];
#pragma unroll
    for (int j = 0; j < 4; ++j) {
      float a = eb[j];
#pragma unroll
      for (int k = 0; k < 6; ++k) a += z[k] * ew[k][j];
      w[j] = fmaxf(a, 0.f);
    }
    float t1 = w[0] + w[1] + w[2] + w[3];
    float t2 = w[0] * w[0] + w[1] * w[1] + w[2] * w[2] + w[3] * w[3];
    t1 = wave_sum(t1); t2 = wave_sum(t2);
    float mu2 = t1 * (1.f / HID);
    float rs2 = rsqrtf(fmaxf(t2 * (1.f / HID) - mu2 * mu2, 0.f) + 1e-5f);
#pragma unroll
    for (int j = 0; j < 4; ++j) acc[j] += (w[j] - mu2) * rs2 * eg[j] + ebe[j];
  }
  float inv = (e1 > e0) ? 1.f / (float)(e1 - e0) : 0.f;
#pragma unroll
  for (int j = 0; j < 4; ++j) h[(size_t)n * HID + lane + 64 * j] = hv[j] + acc[j] * inv;
}

// ---------- f = h @ W  (16 nodes per block, 256 threads) ----------
#define GM 16
__global__ void k_gemm256(const float* __restrict__ h, const float* __restrict__ W,
                          float* __restrict__ f) {
  __shared__ float hs[GM][HID];
  int n0 = blockIdx.x * GM;
  int c = threadIdx.x;
#pragma unroll
  for (int m = 0; m < GM; ++m) hs[m][c] = h[(size_t)(n0 + m) * HID + c];
  __syncthreads();
  float acc[GM];
#pragma unroll
  for (int m = 0; m < GM; ++m) acc[m] = 0.f;
  for (int k = 0; k < HID; ++k) {
    float w = W[k * HID + c];
#pragma unroll
    for (int m = 0; m < GM; ++m) acc[m] += hs[m][k] * w;
  }
#pragma unroll
  for (int m = 0; m < GM; ++m) f[(size_t)(n0 + m) * HID + c] = acc[m];
}

// ---------- el/er (one wave per node) ----------
__global__ void k_elr(const float* __restrict__ f, const float* __restrict__ al,
                      const float* __restrict__ ar, float* __restrict__ el,
                      float* __restrict__ er) {
  int lane = threadIdx.x & 63;
  int n = blockIdx.x * 4 + (threadIdx.x >> 6);
  if (n >= N_FACES) return;
  float4 v = reinterpret_cast<const float4*>(f)[(size_t)n * 64 + lane];
  float4 a = reinterpret_cast<const float4*>(al)[lane];
  float4 b = reinterpret_cast<const float4*>(ar)[lane];
  float pl = v.x * a.x + v.y * a.y + v.z * a.z + v.w * a.w;
  float pr = v.x * b.x + v.y * b.y + v.z * b.z + v.w * b.w;
#pragma unroll
  for (int o = 1; o < 16; o <<= 1) {
    pl += __shfl_xor(pl, o, 64);
    pr += __shfl_xor(pr, o, 64);
  }
  if ((lane & 15) == 0) {
    el[n * 4 + (lane >> 4)] = pl;
    er[n * 4 + (lane >> 4)] = pr;
  }
}

// ---------- GAT: single fused edge pass ----------
__global__ void k_gat(const float* __restrict__ f, const float* __restrict__ el,
                      const float* __restrict__ er, const int* __restrict__ row_ptr,
                      const int* __restrict__ csrc,
                      const float* __restrict__ bias, const float* __restrict__ g,
                      const float* __restrict__ be, float* __restrict__ h) {
  int lane = threadIdx.x & 63;
  int n = blockIdx.x * 4 + (threadIdx.x >> 6);
  if (n >= N_FACES) return;
  int e0 = row_ptr[n], e1 = row_ptr[n + 1];
  float4 ern = reinterpret_cast<const float4*>(er)[n];

  float s0 = 0.f, s1 = 0.f, s2 = 0.f, s3 = 0.f;
  float a0 = 0.f, a1 = 0.f, a2 = 0.f, a3 = 0.f;
  for (int t = e0; t < e1; ++t) {
    int s = csrc[t];
    float4 e4 = reinterpret_cast<const float4*>(el)[s];
    float w, p;
    const float* fr = f + (size_t)s * HID;
    w = e4.x + ern.x; w = w > 0.f ? w : 0.2f * w; p = __expf(w); s0 += p; a0 += fr[lane]       * p;
    w = e4.y + ern.y; w = w > 0.f ? w : 0.2f * w; p = __expf(w); s1 += p; a1 += fr[lane + 64]  * p;
    w = e4.z + ern.z; w = w > 0.f ? w : 0.2f * w; p = __expf(w); s2 += p; a2 += fr[lane + 128] * p;
    w = e4.w + ern.w; w = w > 0.f ? w : 0.2f * w; p = __expf(w); s3 += p; a3 += fr[lane + 192] * p;
  }
  a0 *= (s0 > 0.f ? 1.f / s0 : 0.f);
  a1 *= (s1 > 0.f ? 1.f / s1 : 0.f);
  a2 *= (s2 > 0.f ? 1.f / s2 : 0.f);
  a3 *= (s3 > 0.f ? 1.f / s3 : 0.f);

  float y0 = fmaxf(a0 + bias[lane], 0.f);
  float y1 = fmaxf(a1 + bias[lane + 64], 0.f);
  float y2 = fmaxf(a2 + bias[lane + 128], 0.f);
  float y3 = fmaxf(a3 + bias[lane + 192], 0.f);
  float s = y0 + y1 + y2 + y3;
  float q = y0 * y0 + y1 * y1 + y2 * y2 + y3 * y3;
  s = wave_sum(s); q = wave_sum(q);
  float mu = s * (1.f / HID);
  float rs = rsqrtf(fmaxf(q * (1.f / HID) - mu * mu, 0.f) + 1e-5f);
  size_t base = (size_t)n * HID;
  h[base + lane]       = (y0 - mu) * rs * g[lane]       + be[lane];
  h[base + lane + 64]  = (y1 - mu) * rs * g[lane + 64]  + be[lane + 64];
  h[base + lane + 128] = (y2 - mu) * rs * g[lane + 128] + be[lane + 128];
  h[base + lane + 192] = (y3 - mu) * rs * g[lane + 192] + be[lane + 192];
}

// ---------- gate scores ----------
__global__ void k_gate(const float* __restrict__ h, const float* __restrict__ gw,
                       const float* __restrict__ gb, float* __restrict__ gate) {
  int lane = threadIdx.x & 63;
  int n = blockIdx.x * 4 + (threadIdx.x >> 6);
  if (n >= N_FACES) return;
  float4 v = reinterpret_cast<const float4*>(h)[(size_t)n * 64 + lane];
  float4 w = reinterpret_cast<const float4*>(gw)[lane];
  float p = v.x * w.x + v.y * w.y + v.z * w.z + v.w * w.w;
  p = wave_sum(p);
  if (lane == 0) gate[n] = p + gb[0];
}

// ---------- per-graph max of gate: LDS pre-reduction, then global atomics ----------
__global__ void k_gmax(const float* __restrict__ gate, const int* __restrict__ gid,
                       unsigned* __restrict__ gmax_u) {
  __shared__ unsigned sm[NB];
  int t = threadIdx.x;
  if (t < NB) sm[t] = 0u;
  __syncthreads();
  int n = blockIdx.x * blockDim.x + t;
  if (n < N_FACES) atomicMax(&sm[gid[n]], enc_ord(gate[n]));
  __syncthreads();
  if (t < NB && sm[t] != 0u) atomicMax(&gmax_u[t], sm[t]);
}

// ---------- parallel weighted pooling (unnormalized) ----------
#define PCHUNK 125
__global__ void k_psum(const float* __restrict__ h, const float* __restrict__ gate,
                       const int* __restrict__ gid, const unsigned* __restrict__ gmax_u,
                       float* __restrict__ praw, float* __restrict__ gs) {
  int t = threadIdx.x;
  int n0 = blockIdx.x * PCHUNK;
  int n1 = n0 + PCHUNK;
  if (n1 > N_FACES) n1 = N_FACES;
  if (n0 >= N_FACES) return;
  int cur = gid[n0];
  float gm = dec_ord(gmax_u[cur]);
  float acc = 0.f, wsum = 0.f;
  for (int n = n0; n < n1; ++n) {
    int g = gid[n];
    if (g != cur) {
      atomicAdd(&praw[cur * HID + t], acc);
      if (t == 0) atomicAdd(&gs[cur], wsum);
      acc = 0.f; wsum = 0.f; cur = g; gm = dec_ord(gmax_u[cur]);
    }
    float w = __expf(gate[n] - gm);
    acc += w * h[(size_t)n * HID + t];
    wsum += w;
  }
  atomicAdd(&praw[cur * HID + t], acc);
  if (t == 0) atomicAdd(&gs[cur], wsum);
}

__global__ void k_poolnorm(const float* __restrict__ praw, const float* __restrict__ gs,
                           float* __restrict__ pooled) {
  int b = blockIdx.x, c = threadIdx.x;
  pooled[b * HID + c] = praw[b * HID + c] / gs[b];
}

// ---------- output projection + LN ----------
__global__ void k_out(const float* __restrict__ pooled, const float* __restrict__ oW,
                      const float* __restrict__ oB, const float* __restrict__ oG,
                      const float* __restrict__ oBe, float* __restrict__ feat) {
  int b = blockIdx.x;
  int o = threadIdx.x;  // 512 threads
  int lane = o & 63, wid = o >> 6;
  __shared__ float p[HID];
  __shared__ float partS[8], partQ[8];
  __shared__ float shMu, shRs;
  if (o < HID) p[o] = pooled[b * HID + o];
  __syncthreads();
  float a = oB[o];
  for (int k = 0; k < HID; ++k) a += p[k] * oW[k * NOUT + o];
  float y = fmaxf(a, 0.f);
  float s = wave_sum(y), q = wave_sum(y * y);
  if (lane == 0) { partS[wid] = s; partQ[wid] = q; }
  __syncthreads();
  if (o == 0) {
    float S = 0.f, Q = 0.f;
#pragma unroll
    for (int i = 0; i < 8; ++i) { S += partS[i]; Q += partQ[i]; }
    float mu = S * (1.f / NOUT);
    shMu = mu;
    shRs = rsqrtf(fmaxf(Q * (1.f / NOUT) - mu * mu, 0.f) + 1e-5f);
  }
  __syncthreads();
  feat[b * NOUT + o] = (y - shMu) * shRs * oG[o] + oBe[o];
}

extern "C" void kernel_launch(void* const* d_in, const int* in_sizes, int n_in,
                              void* d_out, int out_size, void* d_ws, size_t ws_size,
                              hipStream_t stream) {
  (void)in_sizes; (void)n_in; (void)out_size; (void)ws_size;
  const float* x_face    = (const float*)d_in[0];
  const float* x_edge    = (const float*)d_in[1];
  const float* face_W    = (const float*)d_in[2];
  const float* face_b    = (const float*)d_in[3];
  const float* face_g    = (const float*)d_in[4];
  const float* face_beta = (const float*)d_in[5];
  const float* edge_W    = (const float*)d_in[6];
  const float* edge_b    = (const float*)d_in[7];
  const float* edge_g    = (const float*)d_in[8];
  const float* edge_beta = (const float*)d_in[9];
  const float* g0_W      = (const float*)d_in[10];
  const float* g0_al     = (const float*)d_in[11];
  const float* g0_ar     = (const float*)d_in[12];
  const float* g0_bias   = (const float*)d_in[13];
  const float* g0_g      = (const float*)d_in[14];
  const float* g0_beta   = (const float*)d_in[15];
  const float* g1_W      = (const float*)d_in[16];
  const float* g1_al     = (const float*)d_in[17];
  const float* g1_ar     = (const float*)d_in[18];
  const float* g1_bias   = (const float*)d_in[19];
  const float* g1_g      = (const float*)d_in[20];
  const float* g1_beta   = (const float*)d_in[21];
  const float* gate_W    = (const float*)d_in[22];
  const float* gate_b    = (const float*)d_in[23];
  const float* out_W     = (const float*)d_in[24];
  const float* out_b     = (const float*)d_in[25];
  const float* out_g     = (const float*)d_in[26];
  const float* out_beta  = (const float*)d_in[27];
  const int*   src       = (const int*)d_in[28];
  const int*   dst       = (const int*)d_in[29];
  const int*   gid       = (const int*)d_in[30];

  char* ws = (char*)d_ws;
  size_t off = 0;
  auto take = [&](size_t bytes) -> char* {
    char* pp = ws + off;
    off += (bytes + 255) & ~(size_t)255;
    return pp;
  };
  int*      cnt      = (int*)take((size_t)N_FACES * 4);
  int*      fill     = (int*)take((size_t)N_FACES * 4);
  int*      row_ptr  = (int*)take((size_t)(N_FACES + 1) * 4);
  int*      bsum     = (int*)take((size_t)SCAN_NB * 4);
  int*      csr_src  = (int*)take((size_t)N_EDGES * 4);
  float*    csr_xe   = (float*)take((size_t)N_EDGES * 6 * 4);
  unsigned* gmax_u   = (unsigned*)take(64);
  float*    gs       = (float*)take(64);
  float*    praw     = (float*)take((size_t)NB * HID * 4);
  float*    el       = (float*)take((size_t)N_FACES * 4 * 4);
  float*    er       = (float*)take((size_t)N_FACES * 4 * 4);
  float*    gate     = (float*)take((size_t)N_FACES * 4);
  float*    f        = (float*)take((size_t)N_FACES * HID * 4);

  float* outp   = (float*)d_out;
  float* feat   = outp;
  float* h      = outp + NB * NOUT;
  float* pooled = outp + NB * NOUT + (size_t)N_FACES * HID;

  hipMemsetAsync(cnt, 0, (size_t)N_FACES * 4, stream);
  hipMemsetAsync(fill, 0, (size_t)N_FACES * 4, stream);
  hipMemsetAsync(gmax_u, 0, 64, stream);
  hipMemsetAsync(gs, 0, 64, stream);
  hipMemsetAsync(praw, 0, (size_t)NB * HID * 4, stream);

  k_hist<<<(N_EDGES + 255) / 256, 256, 0, stream>>>(dst, cnt);
  k_scan1<<<SCAN_NB, SCAN_B, 0, stream>>>(cnt, bsum);
  k_scan2<<<1, 64, 0, stream>>>(bsum);
  k_scan3<<<SCAN_NB, SCAN_B, 0, stream>>>(cnt, bsum, row_ptr);
  k_scatter<<<(N_EDGES + 255) / 256, 256, 0, stream>>>(dst, src, x_edge, row_ptr,
                                                       fill, csr_xe, csr_src);

  k_encode<<<N_FACES / 4, 256, 0, stream>>>(x_face, csr_xe, face_W, face_b, face_g, face_beta,
                                            edge_W, edge_b, edge_g, edge_beta,
                                            row_ptr, h);
  // GAT layer 0
  k_gemm256<<<N_FACES / GM, 256, 0, stream>>>(h, g0_W, f);
  k_elr<<<N_FACES / 4, 256, 0, stream>>>(f, g0_al, g0_ar, el, er);
  k_gat<<<N_FACES / 4, 256, 0, stream>>>(f, el, er, row_ptr, csr_src,
                                         g0_bias, g0_g, g0_beta, h);
  // GAT layer 1
  k_gemm256<<<N_FACES / GM, 256, 0, stream>>>(h, g1_W, f);
  k_elr<<<N_FACES / 4, 256, 0, stream>>>(f, g1_al, g1_ar, el, er);
  k_gat<<<N_FACES / 4, 256, 0, stream>>>(f, el, er, row_ptr, csr_src,
                                         g1_bias, g1_g, g1_beta, h);
  // pooling + output head
  k_gate<<<N_FACES / 4, 256, 0, stream>>>(h, gate_W, gate_b, gate);
  k_gmax<<<(N_FACES + 255) / 256, 256, 0, stream>>>(gate, gid, gmax_u);
  k_psum<<<(N_FACES + PCHUNK - 1) / PCHUNK, 256, 0, stream>>>(h, gate, gid, gmax_u, praw, gs);
  k_poolnorm<<<NB, HID, 0, stream>>>(praw, gs, pooled);
  k_out<<<NB, NOUT, 0, stream>>>(pooled, out_W, out_b, out_g, out_beta, feat);
}